// Round 5
// baseline (453.859 us; speedup 1.0000x reference)
//
#include <hip/hip_runtime.h>
#include <hip/hip_cooperative_groups.h>

namespace cg = cooperative_groups;

// Problem constants
#define B_ 4
#define C_ 64
#define F_ 64
#define T_ 128
#define IC_ 32
#define N_ 8192
#define M_ 2048

// Scratch layout (float units; all fp32 intermediates)
#define OFF_U      0           // B*N
#define OFF_PSI2   32768       // B*M*IC, layout [b][m][c]
#define OFF_V      294912      // B*M
#define OFF_VS     303104      // B*M sorted v (descending)
#define OFF_Q0     311296      // B*2049*64 prefix of z, layout [b][k][o]
#define OFF_Q1     835840      // B*2049*64 prefix of v*z
#define WS_FLOATS  1360384     // 5.44 MB static device scratch (d_ws too small to trust)

__device__ __align__(16) float g_ws[WS_FLOATS];
__device__ int g_perm[B_ * M_];

// ---------------------------------------------------------------------------
// Phase A: psi/phi conv + 2x2 maxpool -> psi2, v; collapsed theta -> u
// 512 blocks x 256 thr. block=(b, fh, col-quarter). smem use: 8320 floats.
// ---------------------------------------------------------------------------
__device__ __forceinline__ void phase_front(float* smem,
    const float* __restrict__ x,
    const float* __restrict__ psi_w, const float* __restrict__ psi_b,
    const float* __restrict__ theta_w, const float* __restrict__ theta_b,
    const float* __restrict__ phi_w, const float* __restrict__ phi_b,
    const float* __restrict__ h0_w, const float* __restrict__ h1_w,
    const float* __restrict__ h2_w)
{
    float* __restrict__ ws = g_ws;
    float* xs   = smem;          // 4096: [c][r2(2)][col(32)]
    float* pw   = smem + 4096;   // 2080 (pitch 65)
    float* fw   = smem + 6176;   // 2080 (pitch 65)
    float* wt_l = smem + 8256;   // 64

    const int tid = threadIdx.x;
    const int bid = blockIdx.x;
    const int b = bid >> 7;
    const int rem = bid & 127;
    const int fh = rem >> 2;        // [0,32)
    const int q = rem & 3;          // col-quarter [0,4)
    const int c0 = q * 32;

    // stage x tile (float4): 64 ch x rows {2fh,2fh+1} x cols [c0,c0+32)
    for (int idx = tid; idx < 1024; idx += 256) {
        const int c = idx >> 4, r2 = (idx >> 3) & 1, t4 = idx & 7;
        const float4 v = *(const float4*)&x[(((size_t)b * 64 + c) * 64 + (2 * fh + r2)) * 128 + c0 + 4 * t4];
        *(float4*)&xs[c * 64 + r2 * 32 + 4 * t4] = v;
    }
    for (int idx = tid; idx < 2048; idx += 256) {
        const int o = idx >> 6, c = idx & 63;
        pw[o * 65 + c] = psi_w[idx];
        fw[o * 65 + c] = phi_w[idx];
    }
    if (tid < 64) {
        float acc = 0.f;
        for (int o2 = 0; o2 < 32; ++o2)
            acc += h0_w[o2] * theta_w[o2 * 64 + tid];
        wt_l[tid] = acc;
    }
    __syncthreads();

    const float h20 = h2_w[0], h21 = h2_w[1];

    // conv + pool: thread=(o in [0,32), g in [0,8)); half-cols 2g, 2g+1 (cols 4g..4g+3)
    {
        const int o = tid & 31, g = tid >> 5;
        const float pb = psi_b[o], fb = phi_b[o], h1 = h1_w[o];
        float sp[2][4] = {{0,0,0,0},{0,0,0,0}};
        float sf[2][4] = {{0,0,0,0},{0,0,0,0}};
        for (int c = 0; c < 64; ++c) {
            const float pwv = pw[o * 65 + c];
            const float fwv = fw[o * 65 + c];
            const float4 r0v = *(const float4*)&xs[c * 64 + 4 * g];        // row0 cols 4g..4g+3
            const float4 r1v = *(const float4*)&xs[c * 64 + 32 + 4 * g];   // row1
            sp[0][0] += pwv * r0v.x; sp[0][1] += pwv * r0v.y;
            sp[0][2] += pwv * r1v.x; sp[0][3] += pwv * r1v.y;
            sp[1][0] += pwv * r0v.z; sp[1][1] += pwv * r0v.w;
            sp[1][2] += pwv * r1v.z; sp[1][3] += pwv * r1v.w;
            sf[0][0] += fwv * r0v.x; sf[0][1] += fwv * r0v.y;
            sf[0][2] += fwv * r1v.x; sf[0][3] += fwv * r1v.y;
            sf[1][0] += fwv * r0v.z; sf[1][1] += fwv * r0v.w;
            sf[1][2] += fwv * r1v.z; sf[1][3] += fwv * r1v.w;
        }
#pragma unroll
        for (int h = 0; h < 2; ++h) {
            const int hc = 2 * g + h;
            const float psiv = fmaxf(fmaxf(sp[h][0], sp[h][1]), fmaxf(sp[h][2], sp[h][3])) + pb;
            const float phiv = fmaxf(fmaxf(sf[h][0], sf[h][1]), fmaxf(sf[h][2], sf[h][3])) + fb;
            const int m = fh * 64 + q * 16 + hc;
            ws[OFF_PSI2 + ((size_t)b * 2048 + m) * 32 + o] = psiv;
            float tv = h1 * phiv;
            for (int mask = 1; mask < 32; mask <<= 1)
                tv += __shfl_xor(tv, mask, 64);
            if (o == 0) {
                const float bpos = h20 * (fh * (1.0f / 31.0f))
                                 + h21 * ((q * 16 + hc) * (1.0f / 63.0f));
                ws[OFF_V + b * 2048 + m] = tv - bpos;
            }
        }
    }

    // u[b,n] for the 64 full positions of this tile
    if (tid < 64) {
        const int r2 = tid >> 5, tl = tid & 31;
        float acc = 0.f;
        for (int c = 0; c < 64; ++c)
            acc += xs[c * 64 + r2 * 32 + tl] * wt_l[c];
        float tb_ = 0.f;
        for (int o2 = 0; o2 < 32; ++o2)
            tb_ += h0_w[o2] * theta_b[o2];
        const int f = 2 * fh + r2, tt = c0 + tl;
        const int n = f * 128 + tt;
        const float a = h20 * (f * (1.0f / 63.0f)) + h21 * (tt * (1.0f / 127.0f));
        ws[OFF_U + b * 8192 + n] = acc + tb_ + a;
    }
}

// ---------------------------------------------------------------------------
// Phase B: barrier-free rank sort (descending, index tie-break)
// 512 blocks x 256 thr. block=(b, chunk of 16 m's). smem use: 2304 floats.
// ---------------------------------------------------------------------------
__device__ __forceinline__ void phase_rank(float* smem)
{
    float* __restrict__ ws = g_ws;
    float* vl = smem;                   // 2048
    int* part = (int*)(smem + 2048);    // 256
    const int tid = threadIdx.x;
    const int b = blockIdx.x >> 7, chunk = blockIdx.x & 127;
    const float* v = ws + OFF_V + b * 2048;
    for (int i = tid; i < 2048; i += 256) vl[i] = v[i];
    __syncthreads();

    const int ml = tid & 15, jq = tid >> 4;
    const int m = chunk * 16 + ml;
    const float vm = vl[m];
    int cnt = 0;
    const float4* v4 = (const float4*)vl;
    const int j0 = jq * 32;
    for (int j4 = j0; j4 < j0 + 32; ++j4) {
        const float4 vv = v4[j4];
        const int jb = j4 * 4;
        cnt += (vv.x > vm) || (vv.x == vm && (jb    ) < m);
        cnt += (vv.y > vm) || (vv.y == vm && (jb + 1) < m);
        cnt += (vv.z > vm) || (vv.z == vm && (jb + 2) < m);
        cnt += (vv.w > vm) || (vv.w == vm && (jb + 3) < m);
    }
    part[tid] = cnt;
    __syncthreads();
    if (tid < 16) {
        int r = 0;
#pragma unroll
        for (int j = 0; j < 16; ++j) r += part[j * 16 + tid];
        ws[OFF_VS + b * 2048 + r] = vl[chunk * 16 + tid];
        g_perm[b * 2048 + r] = chunk * 16 + tid;
    }
}

// ---------------------------------------------------------------------------
// Phase C: z = W_w[o,:] . psi (sorted), block scan -> Q0/Q1[b][k][o]
// active blocks 0..255 = (b,o), 256 thr, 8 items/thr. smem use: 544 floats.
// ---------------------------------------------------------------------------
__device__ __forceinline__ void phase_scan(float* smem, const float* __restrict__ W_w)
{
    if (blockIdx.x >= 256) return;      // uniform per block: safe with barriers below
    float* __restrict__ ws = g_ws;
    float* a0 = smem;                   // 256
    float* a1 = smem + 256;             // 256
    float* Wrow = smem + 512;           // 32
    const int tid = threadIdx.x;
    const int b = blockIdx.x >> 6, o = blockIdx.x & 63;
    if (tid < 32) Wrow[tid] = W_w[o * 33 + tid];   // W_w is (64,33); col 32 = zero channel
    __syncthreads();

    const int* perm = g_perm + b * 2048;
    const float* vs = ws + OFF_VS + b * 2048;
    const float* psi2 = ws + OFF_PSI2 + (size_t)b * 2048 * 32;

    float zl[8], vlv[8];
    float s0 = 0.f, s1 = 0.f;
    const int base = tid * 8;
#pragma unroll
    for (int qq = 0; qq < 8; ++qq) {
        const int i = base + qq;
        const int mp = perm[i];
        const float4* pr = (const float4*)(psi2 + (size_t)mp * 32);
        float z = 0.f;
#pragma unroll
        for (int w = 0; w < 8; ++w) {
            const float4 p4 = pr[w];
            z += Wrow[4 * w] * p4.x + Wrow[4 * w + 1] * p4.y
               + Wrow[4 * w + 2] * p4.z + Wrow[4 * w + 3] * p4.w;
        }
        const float vv = vs[i];
        zl[qq] = z; vlv[qq] = vv;
        s0 += z; s1 += vv * z;
    }
    a0[tid] = s0; a1[tid] = s1;
    __syncthreads();
    for (int off = 1; off < 256; off <<= 1) {
        const float t0_ = (tid >= off) ? a0[tid - off] : 0.f;
        const float t1_ = (tid >= off) ? a1[tid - off] : 0.f;
        __syncthreads();
        a0[tid] += t0_; a1[tid] += t1_;
        __syncthreads();
    }
    float r0 = a0[tid] - s0, r1 = a1[tid] - s1;   // exclusive base
    float* Q0 = ws + OFF_Q0 + (size_t)b * 2049 * 64;
    float* Q1 = ws + OFF_Q1 + (size_t)b * 2049 * 64;
#pragma unroll
    for (int qq = 0; qq < 8; ++qq) {
        r0 += zl[qq]; r1 += vlv[qq] * zl[qq];
        Q0[(size_t)(base + qq + 1) * 64 + o] = r0;
        Q1[(size_t)(base + qq + 1) * 64 + o] = r1;
    }
    if (tid == 0) { Q0[o] = 0.f; Q1[o] = 0.f; }
}

// ---------------------------------------------------------------------------
// Phase D: binary search k(n), gather Q rows, fold W_b+BN, LDS transpose,
// add x, store. 512 blocks x 256 thr. smem use: 4288 floats.
// ---------------------------------------------------------------------------
__device__ __forceinline__ void phase_out(float* smem,
    const float* __restrict__ x,
    const float* __restrict__ W_b,
    const float* __restrict__ bn_g, const float* __restrict__ bn_b,
    const float* __restrict__ bn_m, const float* __restrict__ bn_v,
    float* __restrict__ out)
{
    const float* __restrict__ ws = g_ws;
    float* tileb = smem;                   // 4160: [o][n] pitch 65
    int* karr = (int*)(smem + 4160);       // 64
    float* uarr = smem + 4224;             // 64

    const int tid = threadIdx.x;
    const int b = blockIdx.x >> 7, tile = blockIdx.x & 127;
    const int n0 = tile * 64;

    const float* vs = ws + OFF_VS + b * 2048;
    if (tid < 64) {
        const float u = ws[OFF_U + b * 8192 + n0 + tid];
        const float thr = -u;
        int lo = 0, hi = 2048;
        while (lo < hi) {                  // first idx with vs[idx] <= -u (descending)
            const int mid = (lo + hi) >> 1;
            if (vs[mid] > thr) lo = mid + 1; else hi = mid;
        }
        karr[tid] = lo;
        uarr[tid] = u;
    }
    __syncthreads();

    const int lane = tid & 63, w = tid >> 6;   // w in [0,4)
    const float inv = bn_g[lane] * __frsqrt_rn(bn_v[lane] + 1e-5f);
    const float sft = W_b[lane] * inv + bn_b[lane] - bn_m[lane] * inv;
    const float* Q0 = ws + OFF_Q0 + (size_t)b * 2049 * 64;
    const float* Q1 = ws + OFF_Q1 + (size_t)b * 2049 * 64;

    for (int nl = w; nl < 64; nl += 4) {
        const int k = karr[nl];
        const float u = uarr[nl];
        const float q0 = Q0[(size_t)k * 64 + lane];   // 256B coalesced row
        const float q1 = Q1[(size_t)k * 64 + lane];
        const float raw = (u * q0 + q1) * (1.0f / 2048.0f);
        tileb[lane * 65 + nl] = raw * inv + sft;
    }
    __syncthreads();

    for (int idx = tid; idx < 2048; idx += 256) {     // float2 epilogue
        const int o = idx >> 5, j2 = idx & 31;
        const size_t gi = ((size_t)b * 64 + o) * 8192 + n0 + 2 * j2;
        const float2 xv = *(const float2*)&x[gi];
        float2 r;
        r.x = tileb[o * 65 + 2 * j2] + xv.x;
        r.y = tileb[o * 65 + 2 * j2 + 1] + xv.y;
        *(float2*)&out[gi] = r;
    }
}

// ---------------------------------------------------------------------------
// Fused cooperative kernel: 512 blocks x 256 threads, 2 blocks/CU co-resident
// ---------------------------------------------------------------------------
__global__ __launch_bounds__(256, 2) void k_fused(
    const float* x,
    const float* psi_w, const float* psi_b,
    const float* theta_w, const float* theta_b,
    const float* phi_w, const float* phi_b,
    const float* h0_w, const float* h1_w, const float* h2_w,
    const float* W_w, const float* W_b,
    const float* bn_g, const float* bn_b, const float* bn_m, const float* bn_v,
    float* out)
{
    __shared__ __align__(16) float smem[8384];
    cg::grid_group grid = cg::this_grid();

    phase_front(smem, x, psi_w, psi_b, theta_w, theta_b, phi_w, phi_b, h0_w, h1_w, h2_w);
    __threadfence(); grid.sync();
    phase_rank(smem);
    __threadfence(); grid.sync();
    phase_scan(smem, W_w);
    __threadfence(); grid.sync();
    phase_out(smem, x, W_b, bn_g, bn_b, bn_m, bn_v, out);
}

// ---- Fallback path: the proven 4-kernel pipeline (same phase code) --------
__global__ __launch_bounds__(256) void k1(
    const float* x, const float* psi_w, const float* psi_b,
    const float* theta_w, const float* theta_b,
    const float* phi_w, const float* phi_b,
    const float* h0_w, const float* h1_w, const float* h2_w)
{
    __shared__ __align__(16) float smem[8384];
    phase_front(smem, x, psi_w, psi_b, theta_w, theta_b, phi_w, phi_b, h0_w, h1_w, h2_w);
}
__global__ __launch_bounds__(256) void k2()
{
    __shared__ __align__(16) float smem[2304];
    phase_rank(smem);
}
__global__ __launch_bounds__(256) void k3(const float* W_w)
{
    __shared__ __align__(16) float smem[544];
    phase_scan(smem, W_w);
}
__global__ __launch_bounds__(256) void k4(
    const float* x, const float* W_b,
    const float* bn_g, const float* bn_b, const float* bn_m, const float* bn_v,
    float* out)
{
    __shared__ __align__(16) float smem[4288];
    phase_out(smem, x, W_b, bn_g, bn_b, bn_m, bn_v, out);
}

// ---------------------------------------------------------------------------
extern "C" void kernel_launch(void* const* d_in, const int* in_sizes, int n_in,
                              void* d_out, int out_size, void* d_ws, size_t ws_size,
                              hipStream_t stream)
{
    (void)in_sizes; (void)n_in; (void)out_size; (void)d_ws; (void)ws_size;
    const float* x       = (const float*)d_in[0];
    const float* psi_w   = (const float*)d_in[1];
    const float* psi_b   = (const float*)d_in[2];
    const float* theta_w = (const float*)d_in[3];
    const float* theta_b = (const float*)d_in[4];
    const float* phi_w   = (const float*)d_in[5];
    const float* phi_b   = (const float*)d_in[6];
    const float* h0_w    = (const float*)d_in[7];
    const float* h1_w    = (const float*)d_in[8];
    const float* h2_w    = (const float*)d_in[9];
    const float* W_w     = (const float*)d_in[10];
    const float* W_b     = (const float*)d_in[11];
    const float* bn_g    = (const float*)d_in[12];
    const float* bn_b    = (const float*)d_in[13];
    const float* bn_m    = (const float*)d_in[14];
    const float* bn_v    = (const float*)d_in[15];
    float* out = (float*)d_out;

    void* args[] = {
        (void*)&x, (void*)&psi_w, (void*)&psi_b, (void*)&theta_w, (void*)&theta_b,
        (void*)&phi_w, (void*)&phi_b, (void*)&h0_w, (void*)&h1_w, (void*)&h2_w,
        (void*)&W_w, (void*)&W_b, (void*)&bn_g, (void*)&bn_b, (void*)&bn_m,
        (void*)&bn_v, (void*)&out
    };
    hipError_t e = hipLaunchCooperativeKernel((const void*)k_fused,
                                              dim3(512), dim3(256), args, 0, stream);
    if (e != hipSuccess) {
        (void)hipGetLastError();   // clear sticky error; use proven 4-kernel path
        k1<<<dim3(512), dim3(256), 0, stream>>>(x, psi_w, psi_b, theta_w, theta_b,
                                                phi_w, phi_b, h0_w, h1_w, h2_w);
        k2<<<dim3(512), dim3(256), 0, stream>>>();
        k3<<<dim3(256), dim3(256), 0, stream>>>(W_w);
        k4<<<dim3(512), dim3(256), 0, stream>>>(x, W_b, bn_g, bn_b, bn_m, bn_v, out);
    }
}

// Round 6
// 128.530 us; speedup vs baseline: 3.5312x; 3.5312x over previous
//
#include <hip/hip_runtime.h>

// Problem constants
#define B_ 4
#define C_ 64
#define F_ 64
#define T_ 128
#define IC_ 32
#define N_ 8192
#define M_ 2048

// Scratch layout (float units; all fp32 intermediates)
#define OFF_U      0           // B*N
#define OFF_PSI2   32768       // B*M*IC, layout [b][m][c]
#define OFF_V      294912      // B*M
#define OFF_VS     303104      // B*M sorted v (descending)
#define OFF_Q0     311296      // B*2049*64 prefix of z, layout [b][k][o]
#define OFF_Q1     835840      // B*2049*64 prefix of v*z
#define WS_FLOATS  1360384     // 5.44 MB static device scratch (d_ws too small to trust)

__device__ __align__(16) float g_ws[WS_FLOATS];
__device__ int g_perm[B_ * M_];

// ---------------------------------------------------------------------------
// Kernel 1: psi/phi conv + 2x2 maxpool -> psi2, v; collapsed theta -> u
// 512 blocks x 256 thr. block=(b, fh, col-quarter). LDS ~33 KB -> 2 blk/CU.
// ---------------------------------------------------------------------------
__global__ __launch_bounds__(256) void k1(
    const float* __restrict__ x,
    const float* __restrict__ psi_w, const float* __restrict__ psi_b,
    const float* __restrict__ theta_w, const float* __restrict__ theta_b,
    const float* __restrict__ phi_w, const float* __restrict__ phi_b,
    const float* __restrict__ h0_w, const float* __restrict__ h1_w,
    const float* __restrict__ h2_w)
{
    float* __restrict__ ws = g_ws;
    __shared__ __align__(16) float xs[4096];   // [c][r2(2)][col(32)]
    __shared__ float pw[32 * 65];              // pitch 65
    __shared__ float fw[32 * 65];
    __shared__ float wt_l[64];

    const int tid = threadIdx.x;
    const int bid = blockIdx.x;
    const int b = bid >> 7;
    const int rem = bid & 127;
    const int fh = rem >> 2;        // [0,32)
    const int q = rem & 3;          // col-quarter [0,4)
    const int c0 = q * 32;

    // stage x tile (float4): 64 ch x rows {2fh,2fh+1} x cols [c0,c0+32)
    for (int idx = tid; idx < 1024; idx += 256) {
        const int c = idx >> 4, r2 = (idx >> 3) & 1, t4 = idx & 7;
        const float4 v = *(const float4*)&x[(((size_t)b * 64 + c) * 64 + (2 * fh + r2)) * 128 + c0 + 4 * t4];
        *(float4*)&xs[c * 64 + r2 * 32 + 4 * t4] = v;
    }
    for (int idx = tid; idx < 2048; idx += 256) {
        const int o = idx >> 6, c = idx & 63;
        pw[o * 65 + c] = psi_w[idx];
        fw[o * 65 + c] = phi_w[idx];
    }
    if (tid < 64) {
        float acc = 0.f;
        for (int o2 = 0; o2 < 32; ++o2)
            acc += h0_w[o2] * theta_w[o2 * 64 + tid];
        wt_l[tid] = acc;
    }
    __syncthreads();

    const float h20 = h2_w[0], h21 = h2_w[1];

    // conv + pool: thread=(o in [0,32), g in [0,8)); half-cols 2g, 2g+1
    {
        const int o = tid & 31, g = tid >> 5;
        const float pb = psi_b[o], fb = phi_b[o], h1 = h1_w[o];
        float sp[2][4] = {{0,0,0,0},{0,0,0,0}};
        float sf[2][4] = {{0,0,0,0},{0,0,0,0}};
        for (int c = 0; c < 64; ++c) {
            const float pwv = pw[o * 65 + c];
            const float fwv = fw[o * 65 + c];
            const float4 r0v = *(const float4*)&xs[c * 64 + 4 * g];        // row0 cols 4g..4g+3
            const float4 r1v = *(const float4*)&xs[c * 64 + 32 + 4 * g];   // row1
            sp[0][0] += pwv * r0v.x; sp[0][1] += pwv * r0v.y;
            sp[0][2] += pwv * r1v.x; sp[0][3] += pwv * r1v.y;
            sp[1][0] += pwv * r0v.z; sp[1][1] += pwv * r0v.w;
            sp[1][2] += pwv * r1v.z; sp[1][3] += pwv * r1v.w;
            sf[0][0] += fwv * r0v.x; sf[0][1] += fwv * r0v.y;
            sf[0][2] += fwv * r1v.x; sf[0][3] += fwv * r1v.y;
            sf[1][0] += fwv * r0v.z; sf[1][1] += fwv * r0v.w;
            sf[1][2] += fwv * r1v.z; sf[1][3] += fwv * r1v.w;
        }
#pragma unroll
        for (int h = 0; h < 2; ++h) {
            const int hc = 2 * g + h;
            const float psiv = fmaxf(fmaxf(sp[h][0], sp[h][1]), fmaxf(sp[h][2], sp[h][3])) + pb;
            const float phiv = fmaxf(fmaxf(sf[h][0], sf[h][1]), fmaxf(sf[h][2], sf[h][3])) + fb;
            const int m = fh * 64 + q * 16 + hc;
            ws[OFF_PSI2 + ((size_t)b * 2048 + m) * 32 + o] = psiv;
            float tv = h1 * phiv;
            for (int mask = 1; mask < 32; mask <<= 1)
                tv += __shfl_xor(tv, mask, 64);
            if (o == 0) {
                const float bpos = h20 * (fh * (1.0f / 31.0f))
                                 + h21 * ((q * 16 + hc) * (1.0f / 63.0f));
                ws[OFF_V + b * 2048 + m] = tv - bpos;
            }
        }
    }

    // u[b,n] for the 64 full positions of this tile
    if (tid < 64) {
        const int r2 = tid >> 5, tl = tid & 31;
        float acc = 0.f;
        for (int c = 0; c < 64; ++c)
            acc += xs[c * 64 + r2 * 32 + tl] * wt_l[c];
        float tb_ = 0.f;
        for (int o2 = 0; o2 < 32; ++o2)
            tb_ += h0_w[o2] * theta_b[o2];
        const int f = 2 * fh + r2, tt = c0 + tl;
        const int n = f * 128 + tt;
        const float a = h20 * (f * (1.0f / 63.0f)) + h21 * (tt * (1.0f / 127.0f));
        ws[OFF_U + b * 8192 + n] = acc + tb_ + a;
    }
}

// ---------------------------------------------------------------------------
// Kernel 2: barrier-free rank sort (descending, index tie-break)
// 512 blocks x 256 thr. block=(b, chunk of 16 m's).
// Bank-conflict-free mapping: jq = tid&15, float4 walk with stride 16 ->
// each wave iteration touches 64 consecutive floats (2-way aliasing, free).
// ---------------------------------------------------------------------------
__global__ __launch_bounds__(256) void k2()
{
    float* __restrict__ ws = g_ws;
    __shared__ __align__(16) float vl[2048];
    __shared__ int part[256];
    const int tid = threadIdx.x;
    const int b = blockIdx.x >> 7, chunk = blockIdx.x & 127;
    const float* v = ws + OFF_V + b * 2048;
    for (int i = tid; i < 2048; i += 256) vl[i] = v[i];
    __syncthreads();

    const int ml = tid >> 4;        // m within chunk [0,16)
    const int jq = tid & 15;        // j-segment [0,16)
    const int m = chunk * 16 + ml;
    const float vm = vl[m];
    int cnt = 0;
    const float4* v4 = (const float4*)vl;
#pragma unroll 4
    for (int i = 0; i < 32; ++i) {
        const int j4 = jq + 16 * i;          // strided: wave reads consecutive float4s
        const float4 vv = v4[j4];
        const int jb = j4 * 4;
        cnt += (vv.x > vm) || (vv.x == vm && (jb    ) < m);
        cnt += (vv.y > vm) || (vv.y == vm && (jb + 1) < m);
        cnt += (vv.z > vm) || (vv.z == vm && (jb + 2) < m);
        cnt += (vv.w > vm) || (vv.w == vm && (jb + 3) < m);
    }
    part[tid] = cnt;
    __syncthreads();
    if (tid < 16) {
        int r = 0;
#pragma unroll
        for (int j = 0; j < 16; ++j) r += part[tid * 16 + j];
        ws[OFF_VS + b * 2048 + r] = vl[chunk * 16 + tid];
        g_perm[b * 2048 + r] = chunk * 16 + tid;
    }
}

// ---------------------------------------------------------------------------
// Kernel 3: z = W_w[o,:] . psi (sorted order), scan -> Q0/Q1[b][k][o]
// 256 blocks (b,o), 256 thr, 8 items/thr. Wave shfl-scan + 1 barrier.
// ---------------------------------------------------------------------------
__global__ __launch_bounds__(256) void k3(const float* __restrict__ W_w)
{
    float* __restrict__ ws = g_ws;
    __shared__ float Wrow[32];
    __shared__ float wt0[4], wt1[4];
    const int tid = threadIdx.x;
    const int b = blockIdx.x >> 6, o = blockIdx.x & 63;
    if (tid < 32) Wrow[tid] = W_w[o * 33 + tid];   // W_w is (64,33); col 32 = zero channel
    __syncthreads();

    const int* perm = g_perm + b * 2048;
    const float* vs = ws + OFF_VS + b * 2048;
    const float* psi2 = ws + OFF_PSI2 + (size_t)b * 2048 * 32;

    float zl[8], vlv[8];
    float s0 = 0.f, s1 = 0.f;
    const int base = tid * 8;
#pragma unroll
    for (int qq = 0; qq < 8; ++qq) {
        const int i = base + qq;
        const int mp = perm[i];
        const float4* pr = (const float4*)(psi2 + (size_t)mp * 32);
        float z = 0.f;
#pragma unroll
        for (int w = 0; w < 8; ++w) {
            const float4 p4 = pr[w];
            z += Wrow[4 * w] * p4.x + Wrow[4 * w + 1] * p4.y
               + Wrow[4 * w + 2] * p4.z + Wrow[4 * w + 3] * p4.w;
        }
        const float vv = vs[i];
        zl[qq] = z; vlv[qq] = vv;
        s0 += z; s1 += vv * z;
    }

    // inclusive wave scan (64 lanes) of per-thread sums
    float w0 = s0, w1 = s1;
    const int lane = tid & 63, wv = tid >> 6;
#pragma unroll
    for (int off = 1; off < 64; off <<= 1) {
        const float t0_ = __shfl_up(w0, off, 64);
        const float t1_ = __shfl_up(w1, off, 64);
        if (lane >= off) { w0 += t0_; w1 += t1_; }
    }
    if (lane == 63) { wt0[wv] = w0; wt1[wv] = w1; }
    __syncthreads();
    float base0 = 0.f, base1 = 0.f;
    for (int w = 0; w < wv; ++w) { base0 += wt0[w]; base1 += wt1[w]; }
    float r0 = w0 + base0 - s0, r1 = w1 + base1 - s1;   // exclusive prefix

    float* Q0 = ws + OFF_Q0 + (size_t)b * 2049 * 64;
    float* Q1 = ws + OFF_Q1 + (size_t)b * 2049 * 64;
#pragma unroll
    for (int qq = 0; qq < 8; ++qq) {
        r0 += zl[qq]; r1 += vlv[qq] * zl[qq];
        Q0[(size_t)(base + qq + 1) * 64 + o] = r0;
        Q1[(size_t)(base + qq + 1) * 64 + o] = r1;
    }
    if (tid == 0) { Q0[o] = 0.f; Q1[o] = 0.f; }
}

// ---------------------------------------------------------------------------
// Kernel 4: stage sorted v in LDS, binary search k(n), gather Q rows,
// fold W_b+BN, LDS transpose (pitch 65), add x, store.
// 512 blocks x 256 thr.
// ---------------------------------------------------------------------------
__global__ __launch_bounds__(256) void k4(
    const float* __restrict__ x,
    const float* __restrict__ W_b,
    const float* __restrict__ bn_g, const float* __restrict__ bn_b,
    const float* __restrict__ bn_m, const float* __restrict__ bn_v,
    float* __restrict__ out)
{
    const float* __restrict__ ws = g_ws;
    __shared__ __align__(16) float vsl[2048];
    __shared__ float tileb[64 * 65];   // [o][n] pitch 65
    __shared__ int karr[64];
    __shared__ float uarr[64];

    const int tid = threadIdx.x;
    const int b = blockIdx.x >> 7, tile = blockIdx.x & 127;
    const int n0 = tile * 64;

    const float* vs = ws + OFF_VS + b * 2048;
    for (int i = tid; i < 2048; i += 256) vsl[i] = vs[i];
    __syncthreads();

    if (tid < 64) {
        const float u = ws[OFF_U + b * 8192 + n0 + tid];
        const float thr = -u;
        int lo = 0, hi = 2048;
        while (lo < hi) {                  // first idx with vsl[idx] <= -u (descending)
            const int mid = (lo + hi) >> 1;
            if (vsl[mid] > thr) lo = mid + 1; else hi = mid;
        }
        karr[tid] = lo;
        uarr[tid] = u;
    }
    __syncthreads();

    const int lane = tid & 63, w = tid >> 6;   // w in [0,4)
    const float inv = bn_g[lane] * __frsqrt_rn(bn_v[lane] + 1e-5f);
    const float sft = W_b[lane] * inv + bn_b[lane] - bn_m[lane] * inv;
    const float* Q0 = ws + OFF_Q0 + (size_t)b * 2049 * 64;
    const float* Q1 = ws + OFF_Q1 + (size_t)b * 2049 * 64;

    for (int nl = w; nl < 64; nl += 4) {
        const int k = karr[nl];
        const float u = uarr[nl];
        const float q0 = Q0[(size_t)k * 64 + lane];   // 256B coalesced row
        const float q1 = Q1[(size_t)k * 64 + lane];
        const float raw = (u * q0 + q1) * (1.0f / 2048.0f);
        tileb[lane * 65 + nl] = raw * inv + sft;      // 2-way bank aliasing: free
    }
    __syncthreads();

    for (int idx = tid; idx < 2048; idx += 256) {     // float2 epilogue
        const int o = idx >> 5, j2 = idx & 31;
        const size_t gi = ((size_t)b * 64 + o) * 8192 + n0 + 2 * j2;
        const float2 xv = *(const float2*)&x[gi];
        float2 r;
        r.x = tileb[o * 65 + 2 * j2] + xv.x;
        r.y = tileb[o * 65 + 2 * j2 + 1] + xv.y;
        *(float2*)&out[gi] = r;
    }
}

// ---------------------------------------------------------------------------
extern "C" void kernel_launch(void* const* d_in, const int* in_sizes, int n_in,
                              void* d_out, int out_size, void* d_ws, size_t ws_size,
                              hipStream_t stream)
{
    (void)in_sizes; (void)n_in; (void)out_size; (void)d_ws; (void)ws_size;
    const float* x       = (const float*)d_in[0];
    const float* psi_w   = (const float*)d_in[1];
    const float* psi_b   = (const float*)d_in[2];
    const float* theta_w = (const float*)d_in[3];
    const float* theta_b = (const float*)d_in[4];
    const float* phi_w   = (const float*)d_in[5];
    const float* phi_b   = (const float*)d_in[6];
    const float* h0_w    = (const float*)d_in[7];
    const float* h1_w    = (const float*)d_in[8];
    const float* h2_w    = (const float*)d_in[9];
    const float* W_w     = (const float*)d_in[10];
    const float* W_b     = (const float*)d_in[11];
    const float* bn_g    = (const float*)d_in[12];
    const float* bn_b    = (const float*)d_in[13];
    const float* bn_m    = (const float*)d_in[14];
    const float* bn_v    = (const float*)d_in[15];
    float* out = (float*)d_out;

    k1<<<dim3(512), dim3(256), 0, stream>>>(x, psi_w, psi_b, theta_w, theta_b,
                                            phi_w, phi_b, h0_w, h1_w, h2_w);
    k2<<<dim3(512), dim3(256), 0, stream>>>();
    k3<<<dim3(256), dim3(256), 0, stream>>>(W_w);
    k4<<<dim3(512), dim3(256), 0, stream>>>(x, W_b, bn_g, bn_b, bn_m, bn_v, out);
}

// Round 7
// 127.410 us; speedup vs baseline: 3.5622x; 1.0088x over previous
//
#include <hip/hip_runtime.h>

// Problem constants
#define B_ 4
#define C_ 64
#define F_ 64
#define T_ 128
#define IC_ 32
#define N_ 8192
#define M_ 2048

// Scratch layout (float units; all fp32 intermediates)
#define OFF_U      0           // B*N
#define OFF_PSI2   32768       // B*M*IC, layout [b][m][c]
#define OFF_V      294912      // B*M
#define OFF_VS     303104      // B*M sorted v (descending)
#define OFF_Q01    311296      // B*2049*64 float2 (z-prefix, vz-prefix), layout [b][k][o]
#define WS_FLOATS  1360384     // 5.44 MB static device scratch

__device__ __align__(16) float g_ws[WS_FLOATS];
__device__ int g_perm[B_ * M_];

// ---------------------------------------------------------------------------
// Kernel 1: psi/phi conv + 2x2 maxpool -> psi2, v; collapsed theta -> u
// 512 blocks x 256 thr. block=(b, fh, col-quarter). LDS ~33 KB -> 2 blk/CU.
// Weights staged in [c4][o]*float4 layout: conv inner loop reads them as
// consecutive-per-lane ds_read_b128 (conflict-free), 4x fewer LDS instrs.
// ---------------------------------------------------------------------------
__global__ __launch_bounds__(256) void k1(
    const float* __restrict__ x,
    const float* __restrict__ psi_w, const float* __restrict__ psi_b,
    const float* __restrict__ theta_w, const float* __restrict__ theta_b,
    const float* __restrict__ phi_w, const float* __restrict__ phi_b,
    const float* __restrict__ h0_w, const float* __restrict__ h1_w,
    const float* __restrict__ h2_w)
{
    float* __restrict__ ws = g_ws;
    __shared__ __align__(16) float xs[4096];   // [c][r2(2)][col(32)]
    __shared__ __align__(16) float pw[2048];   // [(c4*32 + o)*4 + j]
    __shared__ __align__(16) float fw[2048];
    __shared__ float wt_l[64];

    const int tid = threadIdx.x;
    const int bid = blockIdx.x;
    const int b = bid >> 7;
    const int rem = bid & 127;
    const int fh = rem >> 2;        // [0,32)
    const int q = rem & 3;          // col-quarter [0,4)
    const int c0 = q * 32;

    // stage x tile (float4): 64 ch x rows {2fh,2fh+1} x cols [c0,c0+32)
    for (int idx = tid; idx < 1024; idx += 256) {
        const int c = idx >> 4, r2 = (idx >> 3) & 1, t4 = idx & 7;
        const float4 v = *(const float4*)&x[(((size_t)b * 64 + c) * 64 + (2 * fh + r2)) * 128 + c0 + 4 * t4];
        *(float4*)&xs[c * 64 + r2 * 32 + 4 * t4] = v;
    }
    // stage weights in float4-grouped layout
    for (int idx = tid; idx < 2048; idx += 256) {
        const int c4 = idx >> 7, o = (idx >> 2) & 31, j = idx & 3;
        pw[idx] = psi_w[o * 64 + 4 * c4 + j];
        fw[idx] = phi_w[o * 64 + 4 * c4 + j];
    }
    if (tid < 64) {
        float acc = 0.f;
        for (int o2 = 0; o2 < 32; ++o2)
            acc += h0_w[o2] * theta_w[o2 * 64 + tid];
        wt_l[tid] = acc;
    }
    __syncthreads();

    const float h20 = h2_w[0], h21 = h2_w[1];

    // conv + pool: thread=(o in [0,32), g in [0,8)); half-cols 2g, 2g+1
    {
        const int o = tid & 31, g = tid >> 5;
        const float pb = psi_b[o], fb = phi_b[o], h1 = h1_w[o];
        const float4* pw4 = (const float4*)pw;
        const float4* fw4 = (const float4*)fw;
        const float4* xs4 = (const float4*)xs;
        float sp[2][4] = {{0,0,0,0},{0,0,0,0}};
        float sf[2][4] = {{0,0,0,0},{0,0,0,0}};
        for (int c4 = 0; c4 < 16; ++c4) {
            const float4 pv = pw4[c4 * 32 + o];    // b128, consecutive per lane
            const float4 fv = fw4[c4 * 32 + o];
            const float* pvf = (const float*)&pv;
            const float* fvf = (const float*)&fv;
#pragma unroll
            for (int j = 0; j < 4; ++j) {
                const int c = 4 * c4 + j;
                const float4 r0 = xs4[c * 16 + g];       // broadcast-ish (2 addr/wave)
                const float4 r1 = xs4[c * 16 + 8 + g];
                const float wp = pvf[j], wf = fvf[j];
                sp[0][0] += wp * r0.x; sp[0][1] += wp * r0.y;
                sp[0][2] += wp * r1.x; sp[0][3] += wp * r1.y;
                sp[1][0] += wp * r0.z; sp[1][1] += wp * r0.w;
                sp[1][2] += wp * r1.z; sp[1][3] += wp * r1.w;
                sf[0][0] += wf * r0.x; sf[0][1] += wf * r0.y;
                sf[0][2] += wf * r1.x; sf[0][3] += wf * r1.y;
                sf[1][0] += wf * r0.z; sf[1][1] += wf * r0.w;
                sf[1][2] += wf * r1.z; sf[1][3] += wf * r1.w;
            }
        }
#pragma unroll
        for (int h = 0; h < 2; ++h) {
            const int hc = 2 * g + h;
            const float psiv = fmaxf(fmaxf(sp[h][0], sp[h][1]), fmaxf(sp[h][2], sp[h][3])) + pb;
            const float phiv = fmaxf(fmaxf(sf[h][0], sf[h][1]), fmaxf(sf[h][2], sf[h][3])) + fb;
            const int m = fh * 64 + q * 16 + hc;
            ws[OFF_PSI2 + ((size_t)b * 2048 + m) * 32 + o] = psiv;
            float tv = h1 * phiv;
            for (int mask = 1; mask < 32; mask <<= 1)
                tv += __shfl_xor(tv, mask, 64);
            if (o == 0) {
                const float bpos = h20 * (fh * (1.0f / 31.0f))
                                 + h21 * ((q * 16 + hc) * (1.0f / 63.0f));
                ws[OFF_V + b * 2048 + m] = tv - bpos;
            }
        }
    }

    // u[b,n] for the 64 full positions of this tile
    if (tid < 64) {
        const int r2 = tid >> 5, tl = tid & 31;
        float acc = 0.f;
        for (int c = 0; c < 64; ++c)
            acc += xs[c * 64 + r2 * 32 + tl] * wt_l[c];
        float tb_ = 0.f;
        for (int o2 = 0; o2 < 32; ++o2)
            tb_ += h0_w[o2] * theta_b[o2];
        const int f = 2 * fh + r2, tt = c0 + tl;
        const int n = f * 128 + tt;
        const float a = h20 * (f * (1.0f / 63.0f)) + h21 * (tt * (1.0f / 127.0f));
        ws[OFF_U + b * 8192 + n] = acc + tb_ + a;
    }
}

// ---------------------------------------------------------------------------
// Kernel 2: barrier-free rank sort (descending, index tie-break)
// 512 blocks x 256 thr. block=(b, chunk of 16 m's). Conflict-free strided walk.
// ---------------------------------------------------------------------------
__global__ __launch_bounds__(256) void k2()
{
    float* __restrict__ ws = g_ws;
    __shared__ __align__(16) float vl[2048];
    __shared__ int part[256];
    const int tid = threadIdx.x;
    const int b = blockIdx.x >> 7, chunk = blockIdx.x & 127;
    const float* v = ws + OFF_V + b * 2048;
    for (int i = tid; i < 2048; i += 256) vl[i] = v[i];
    __syncthreads();

    const int ml = tid >> 4;        // m within chunk [0,16)
    const int jq = tid & 15;        // j-segment [0,16)
    const int m = chunk * 16 + ml;
    const float vm = vl[m];
    int cnt = 0;
    const float4* v4 = (const float4*)vl;
#pragma unroll 4
    for (int i = 0; i < 32; ++i) {
        const int j4 = jq + 16 * i;          // wave reads consecutive float4s
        const float4 vv = v4[j4];
        const int jb = j4 * 4;
        cnt += (vv.x > vm) || (vv.x == vm && (jb    ) < m);
        cnt += (vv.y > vm) || (vv.y == vm && (jb + 1) < m);
        cnt += (vv.z > vm) || (vv.z == vm && (jb + 2) < m);
        cnt += (vv.w > vm) || (vv.w == vm && (jb + 3) < m);
    }
    part[tid] = cnt;
    __syncthreads();
    if (tid < 16) {
        int r = 0;
#pragma unroll
        for (int j = 0; j < 16; ++j) r += part[tid * 16 + j];
        ws[OFF_VS + b * 2048 + r] = vl[chunk * 16 + tid];
        g_perm[b * 2048 + r] = chunk * 16 + tid;
    }
}

// ---------------------------------------------------------------------------
// Kernel 3: z = W_w[o,:] . psi (sorted order), scan -> Q01[b][k][o] (float2)
// 256 blocks (b,o) x 512 thr (8 waves/CU), 4 items/thr. Shfl-scan + 1 barrier.
// ---------------------------------------------------------------------------
__global__ __launch_bounds__(512) void k3(const float* __restrict__ W_w)
{
    float* __restrict__ ws = g_ws;
    __shared__ float Wrow[32];
    __shared__ float wt0[8], wt1[8];
    const int tid = threadIdx.x;
    const int b = blockIdx.x >> 6, o = blockIdx.x & 63;
    if (tid < 32) Wrow[tid] = W_w[o * 33 + tid];   // W_w is (64,33); col 32 = zero channel
    __syncthreads();

    const int* perm = g_perm + b * 2048;
    const float* vs = ws + OFF_VS + b * 2048;
    const float* psi2 = ws + OFF_PSI2 + (size_t)b * 2048 * 32;

    float zl[4], vlv[4];
    float s0 = 0.f, s1 = 0.f;
    const int base = tid * 4;
#pragma unroll
    for (int qq = 0; qq < 4; ++qq) {
        const int i = base + qq;
        const int mp = perm[i];
        const float4* pr = (const float4*)(psi2 + (size_t)mp * 32);
        float z = 0.f;
#pragma unroll
        for (int w = 0; w < 8; ++w) {
            const float4 p4 = pr[w];
            z += Wrow[4 * w] * p4.x + Wrow[4 * w + 1] * p4.y
               + Wrow[4 * w + 2] * p4.z + Wrow[4 * w + 3] * p4.w;
        }
        const float vv = vs[i];
        zl[qq] = z; vlv[qq] = vv;
        s0 += z; s1 += vv * z;
    }

    // inclusive wave scan (64 lanes) of per-thread sums
    float w0 = s0, w1 = s1;
    const int lane = tid & 63, wv = tid >> 6;
#pragma unroll
    for (int off = 1; off < 64; off <<= 1) {
        const float t0_ = __shfl_up(w0, off, 64);
        const float t1_ = __shfl_up(w1, off, 64);
        if (lane >= off) { w0 += t0_; w1 += t1_; }
    }
    if (lane == 63) { wt0[wv] = w0; wt1[wv] = w1; }
    __syncthreads();
    float base0 = 0.f, base1 = 0.f;
    for (int w = 0; w < wv; ++w) { base0 += wt0[w]; base1 += wt1[w]; }
    float r0 = w0 + base0 - s0, r1 = w1 + base1 - s1;   // exclusive prefix

    float2* Q01 = (float2*)(ws + OFF_Q01) + (size_t)b * 2049 * 64;
#pragma unroll
    for (int qq = 0; qq < 4; ++qq) {
        r0 += zl[qq]; r1 += vlv[qq] * zl[qq];
        float2 p; p.x = r0; p.y = r1;
        Q01[(size_t)(base + qq + 1) * 64 + o] = p;
    }
    if (tid == 0) { float2 z2; z2.x = 0.f; z2.y = 0.f; Q01[o] = z2; }
}

// ---------------------------------------------------------------------------
// Kernel 4: stage sorted v in LDS, binary search k(n), gather Q01 rows
// (one dwordx2 per (n,lane)), fold W_b+BN, LDS transpose, add x, store.
// 512 blocks x 512 thr (16 waves/CU).
// ---------------------------------------------------------------------------
__global__ __launch_bounds__(512) void k4(
    const float* __restrict__ x,
    const float* __restrict__ W_b,
    const float* __restrict__ bn_g, const float* __restrict__ bn_b,
    const float* __restrict__ bn_m, const float* __restrict__ bn_v,
    float* __restrict__ out)
{
    const float* __restrict__ ws = g_ws;
    __shared__ __align__(16) float vsl[2048];
    __shared__ float tileb[64 * 65];   // [o][n] pitch 65
    __shared__ int karr[64];
    __shared__ float uarr[64];

    const int tid = threadIdx.x;
    const int b = blockIdx.x >> 7, tile = blockIdx.x & 127;
    const int n0 = tile * 64;

    const float* vs = ws + OFF_VS + b * 2048;
    for (int i = tid; i < 2048; i += 512) vsl[i] = vs[i];
    __syncthreads();

    if (tid < 64) {
        const float u = ws[OFF_U + b * 8192 + n0 + tid];
        const float thr = -u;
        int lo = 0, hi = 2048;
        while (lo < hi) {                  // first idx with vsl[idx] <= -u (descending)
            const int mid = (lo + hi) >> 1;
            if (vsl[mid] > thr) lo = mid + 1; else hi = mid;
        }
        karr[tid] = lo;
        uarr[tid] = u;
    }
    __syncthreads();

    const int lane = tid & 63, w = tid >> 6;   // w in [0,8)
    const float inv = bn_g[lane] * __frsqrt_rn(bn_v[lane] + 1e-5f);
    const float sft = W_b[lane] * inv + bn_b[lane] - bn_m[lane] * inv;
    const float2* Q01 = (const float2*)(ws + OFF_Q01) + (size_t)b * 2049 * 64;

    for (int nl = w; nl < 64; nl += 8) {
        const int k = karr[nl];
        const float u = uarr[nl];
        const float2 qv = Q01[(size_t)k * 64 + lane];  // 512B coalesced row
        const float raw = (u * qv.x + qv.y) * (1.0f / 2048.0f);
        tileb[lane * 65 + nl] = raw * inv + sft;       // 2-way bank aliasing: free
    }
    __syncthreads();

    for (int idx = tid; idx < 2048; idx += 512) {      // float2 epilogue
        const int o = idx >> 5, j2 = idx & 31;
        const size_t gi = ((size_t)b * 64 + o) * 8192 + n0 + 2 * j2;
        const float2 xv = *(const float2*)&x[gi];
        float2 r;
        r.x = tileb[o * 65 + 2 * j2] + xv.x;
        r.y = tileb[o * 65 + 2 * j2 + 1] + xv.y;
        *(float2*)&out[gi] = r;
    }
}

// ---------------------------------------------------------------------------
extern "C" void kernel_launch(void* const* d_in, const int* in_sizes, int n_in,
                              void* d_out, int out_size, void* d_ws, size_t ws_size,
                              hipStream_t stream)
{
    (void)in_sizes; (void)n_in; (void)out_size; (void)d_ws; (void)ws_size;
    const float* x       = (const float*)d_in[0];
    const float* psi_w   = (const float*)d_in[1];
    const float* psi_b   = (const float*)d_in[2];
    const float* theta_w = (const float*)d_in[3];
    const float* theta_b = (const float*)d_in[4];
    const float* phi_w   = (const float*)d_in[5];
    const float* phi_b   = (const float*)d_in[6];
    const float* h0_w    = (const float*)d_in[7];
    const float* h1_w    = (const float*)d_in[8];
    const float* h2_w    = (const float*)d_in[9];
    const float* W_w     = (const float*)d_in[10];
    const float* W_b     = (const float*)d_in[11];
    const float* bn_g    = (const float*)d_in[12];
    const float* bn_b    = (const float*)d_in[13];
    const float* bn_m    = (const float*)d_in[14];
    const float* bn_v    = (const float*)d_in[15];
    float* out = (float*)d_out;

    k1<<<dim3(512), dim3(256), 0, stream>>>(x, psi_w, psi_b, theta_w, theta_b,
                                            phi_w, phi_b, h0_w, h1_w, h2_w);
    k2<<<dim3(512), dim3(256), 0, stream>>>();
    k3<<<dim3(256), dim3(512), 0, stream>>>(W_w);
    k4<<<dim3(512), dim3(512), 0, stream>>>(x, W_b, bn_g, bn_b, bn_m, bn_v, out);
}